// Round 1
// baseline (290.120 us; speedup 1.0000x reference)
//
#include <hip/hip_runtime.h>
#include <math.h>

#define LL 128
#define NEGV (-1e9f)

// workspace offsets (in floats)
constexpr size_t OFF_Q   = 0;          // [3][128][1024]
constexpr size_t OFF_K   = 393216;     // [3][128][1024]
constexpr size_t OFF_V   = 786432;     // [3][128][1024]
constexpr size_t OFF_D0  = 1179648;    // [3][128][1024]
constexpr size_t OFF_D1  = 1572864;    // [3][128][1024]
constexpr size_t OFF_U1  = 1966080;    // [3][128][2048]  (= D1@Wtop + b1)
constexpr size_t OFF_U0  = 2752512;    // [3][128][2048]  (= D0@Wbot)
constexpr size_t OFF_DEC = 3538944;    // [9][128][128]   decision accumulator
constexpr size_t OFF_ATT = 3686400;    // [3][16][128][384]
constexpr size_t OFF_O   = 6045696;    // [3][128][1024]
constexpr size_t OFF_O2  = 6438912;    // [3][128][1024]

// ---------------- generic fp32 tiled GEMM: C[128 or 64-tile] = X@W (+bias) ----
// BM=64, BN=64, BK=16, 256 threads, 4x4 per thread. ldx fixed at 1024.
__device__ __forceinline__ void gemm64_body(
    const float* __restrict__ X, const float* __restrict__ W,
    float* __restrict__ C, const float* __restrict__ bias,
    int ldw, int ldc, int K, int m0, int n0)
{
  __shared__ float Xs[16][68];
  __shared__ float Ws[16][68];
  const int tid = threadIdx.x;
  const int ty = tid >> 4, tx = tid & 15;
  const int xr = tid >> 2, xc = (tid & 3) << 2;
  const int wr = tid >> 4, wc = (tid & 15) << 2;
  float acc[4][4] = {};
  for (int k0 = 0; k0 < K; k0 += 16) {
    float4 xv = *(const float4*)(X + (size_t)(m0 + xr) * 1024 + k0 + xc);
    Xs[xc + 0][xr] = xv.x;
    Xs[xc + 1][xr] = xv.y;
    Xs[xc + 2][xr] = xv.z;
    Xs[xc + 3][xr] = xv.w;
    *(float4*)&Ws[wr][wc] = *(const float4*)(W + (size_t)(k0 + wr) * ldw + n0 + wc);
    __syncthreads();
#pragma unroll
    for (int kk = 0; kk < 16; ++kk) {
      float4 a = *(const float4*)&Xs[kk][ty << 2];
      float4 b = *(const float4*)&Ws[kk][tx << 2];
      float av[4] = {a.x, a.y, a.z, a.w};
      float bv[4] = {b.x, b.y, b.z, b.w};
#pragma unroll
      for (int i2 = 0; i2 < 4; ++i2)
#pragma unroll
        for (int j2 = 0; j2 < 4; ++j2)
          acc[i2][j2] = fmaf(av[i2], bv[j2], acc[i2][j2]);
    }
    __syncthreads();
  }
#pragma unroll
  for (int i2 = 0; i2 < 4; ++i2) {
    const int row = m0 + (ty << 2) + i2;
#pragma unroll
    for (int j2 = 0; j2 < 4; ++j2) {
      const int col = n0 + (tx << 2) + j2;
      float v = acc[i2][j2];
      if (bias) v += bias[col];
      C[(size_t)row * ldc + col] = v;
    }
  }
}

// z: 0..14 -> (stream s = z/5, weight wi = z%5)
__global__ __launch_bounds__(256) void proj_gemm(
    const float* x0, const float* x1, const float* x2,
    const float* wq, const float* wk, const float* wv,
    const float* wd0, const float* wd1, float* ws)
{
  const int z = blockIdx.z;
  const int s = z / 5, wi = z % 5;
  const float* X = (s == 0) ? x0 : ((s == 1) ? x1 : x2);
  const float* W;
  size_t coff;
  switch (wi) {
    case 0:  W = wq;  coff = OFF_Q;  break;
    case 1:  W = wk;  coff = OFF_K;  break;
    case 2:  W = wv;  coff = OFF_V;  break;
    case 3:  W = wd0; coff = OFF_D0; break;
    default: W = wd1; coff = OFF_D1; break;
  }
  float* C = ws + coff + (size_t)s * (LL * 1024);
  gemm64_body(X, W, C, nullptr, 1024, 1024, 1024, blockIdx.y * 64, blockIdx.x * 64);
}

// z: 0..5 -> which = z/3 (0: U1 = D1@Wtop + b1, 1: U0 = D0@Wbot), s = z%3
__global__ __launch_bounds__(256) void u_gemm(const float* w1, const float* b1, float* ws)
{
  const int z = blockIdx.z;
  const int s = z % 3, which = z / 3;
  const float* X = ws + (which == 0 ? OFF_D1 : OFF_D0) + (size_t)s * (LL * 1024);
  const float* W = w1 + (which == 0 ? 0 : (size_t)1024 * 2048);
  float* C = ws + (which == 0 ? OFF_U1 : OFF_U0) + (size_t)s * (LL * 2048);
  const float* bias = (which == 0) ? b1 : nullptr;
  gemm64_body(X, W, C, bias, 2048, 2048, 1024, blockIdx.y * 64, blockIdx.x * 64);
}

// decision accumulator: DECACC[p][q][k] += sum_c relu(U1[j][q][c]+U0[i][k][c]) * wdiff[c]
// grid (ktile=2, qtile=4, z=36: p*4+cchunk), 256 threads, 32q x 64k tile, 2x4 micro
#define RELU_DOT(AV, BV)                                                      \
  (fmaxf(AV.x + BV.x, 0.f) * w4.x + fmaxf(AV.y + BV.y, 0.f) * w4.y +          \
   fmaxf(AV.z + BV.z, 0.f) * w4.z + fmaxf(AV.w + BV.w, 0.f) * w4.w)

__global__ __launch_bounds__(256) void dec_kernel(
    const float* __restrict__ u1base, const float* __restrict__ u0base,
    const float* __restrict__ w2, float* __restrict__ decacc)
{
  __shared__ float U1s[32][132];
  __shared__ float U0s[64][132];
  __shared__ float wds[128];
  const int z = blockIdx.z;
  const int p = z >> 2, cc = z & 3;
  const int i = p / 3, j = p % 3;
  const int k0 = blockIdx.x * 64, q0 = blockIdx.y * 32;
  const float* u1 = u1base + (size_t)j * (LL * 2048) + (size_t)q0 * 2048;
  const float* u0 = u0base + (size_t)i * (LL * 2048) + (size_t)k0 * 2048;
  const int tid = threadIdx.x;
  const int ty = tid >> 4, tx = tid & 15;
  float acc[2][4] = {};
  for (int stage = 0; stage < 4; ++stage) {
    const int cbase = cc * 512 + stage * 128;
    {
      const int r = tid >> 3, cg = (tid & 7) << 4;
      const float* src = u1 + (size_t)r * 2048 + cbase + cg;
#pragma unroll
      for (int t = 0; t < 4; ++t)
        *(float4*)&U1s[r][cg + 4 * t] = *(const float4*)(src + 4 * t);
    }
    {
      const int r = tid >> 2, cg = (tid & 3) << 5;
      const float* src = u0 + (size_t)r * 2048 + cbase + cg;
#pragma unroll
      for (int t = 0; t < 8; ++t)
        *(float4*)&U0s[r][cg + 4 * t] = *(const float4*)(src + 4 * t);
    }
    if (tid < 128) {
      const int c = cbase + tid;
      wds[tid] = w2[2 * c + 1] - w2[2 * c + 0];
    }
    __syncthreads();
#pragma unroll 2
    for (int c4 = 0; c4 < 128; c4 += 4) {
      const float4 w4  = *(const float4*)&wds[c4];
      const float4 a0  = *(const float4*)&U1s[ty][c4];
      const float4 a1  = *(const float4*)&U1s[ty + 16][c4];
      const float4 vb0 = *(const float4*)&U0s[tx][c4];
      const float4 vb1 = *(const float4*)&U0s[tx + 16][c4];
      const float4 vb2 = *(const float4*)&U0s[tx + 32][c4];
      const float4 vb3 = *(const float4*)&U0s[tx + 48][c4];
      acc[0][0] += RELU_DOT(a0, vb0); acc[0][1] += RELU_DOT(a0, vb1);
      acc[0][2] += RELU_DOT(a0, vb2); acc[0][3] += RELU_DOT(a0, vb3);
      acc[1][0] += RELU_DOT(a1, vb0); acc[1][1] += RELU_DOT(a1, vb1);
      acc[1][2] += RELU_DOT(a1, vb2); acc[1][3] += RELU_DOT(a1, vb3);
    }
    __syncthreads();
  }
#pragma unroll
  for (int qi = 0; qi < 2; ++qi)
#pragma unroll
    for (int kj = 0; kj < 4; ++kj) {
      const int q = q0 + ty + 16 * qi;
      const int k = k0 + tx + 16 * kj;
      atomicAdd(&decacc[(size_t)p * (128 * 128) + (size_t)q * 128 + k], acc[qi][kj]);
    }
}

// scores: ATT[i][h][q][j*128+k] = (Q_i[q,h,:]·K_j[k,h,:])/8 + mask
// grid (p=9, h=16, qt=2), 256 threads, 64q x 128k, 4x8 micro
__global__ __launch_bounds__(256) void scores_kernel(
    const float* __restrict__ Qb, const float* __restrict__ Kb,
    const float* __restrict__ decacc, const float* __restrict__ b2,
    float* __restrict__ att)
{
  __shared__ float Qs[64][68];
  __shared__ float Ks[128][68];
  const int p = blockIdx.x, h = blockIdx.y, qt = blockIdx.z;
  const int i = p / 3, j = p % 3;
  const int q0 = qt * 64;
  const float* qptr = Qb + (size_t)i * (LL * 1024) + (size_t)q0 * 1024 + h * 64;
  const float* kptr = Kb + (size_t)j * (LL * 1024) + h * 64;
  const int tid = threadIdx.x;
  {
    const int r = tid >> 2, cg = (tid & 3) << 4;
    const float* src = qptr + (size_t)r * 1024 + cg;
#pragma unroll
    for (int t = 0; t < 4; ++t)
      *(float4*)&Qs[r][cg + 4 * t] = *(const float4*)(src + 4 * t);
  }
  {
    const int r = tid >> 1, cg = (tid & 1) << 5;
    const float* src = kptr + (size_t)r * 1024 + cg;
#pragma unroll
    for (int t = 0; t < 8; ++t)
      *(float4*)&Ks[r][cg + 4 * t] = *(const float4*)(src + 4 * t);
  }
  __syncthreads();
  const int ty = tid >> 4, tx = tid & 15;
  float acc[4][8] = {};
  for (int d = 0; d < 64; d += 4) {
    float4 qv[4], kv[8];
#pragma unroll
    for (int qi = 0; qi < 4; ++qi) qv[qi] = *(const float4*)&Qs[ty + 16 * qi][d];
#pragma unroll
    for (int kj = 0; kj < 8; ++kj) kv[kj] = *(const float4*)&Ks[tx + 16 * kj][d];
#pragma unroll
    for (int qi = 0; qi < 4; ++qi)
#pragma unroll
      for (int kj = 0; kj < 8; ++kj)
        acc[qi][kj] += qv[qi].x * kv[kj].x + qv[qi].y * kv[kj].y +
                       qv[qi].z * kv[kj].z + qv[qi].w * kv[kj].w;
  }
  const float bdiff = b2[1] - b2[0];
#pragma unroll
  for (int qi = 0; qi < 4; ++qi)
#pragma unroll
    for (int kj = 0; kj < 8; ++kj) {
      const int q = q0 + ty + 16 * qi;
      const int k = tx + 16 * kj;
      const float da = decacc[(size_t)p * (128 * 128) + (size_t)q * 128 + k];
      const float s = acc[qi][kj] * 0.125f + ((da + bdiff > 0.f) ? NEGV : 0.f);
      att[(((size_t)i * 16 + h) * 128 + q) * 384 + j * 128 + k] = s;
    }
}

// row softmax over 384; one wave per row
__global__ __launch_bounds__(256) void softmax_kernel(float* __restrict__ att)
{
  const int wave = threadIdx.x >> 6, lane = threadIdx.x & 63;
  const int row = blockIdx.x * 4 + wave;  // 0..6143
  float* ptr = att + (size_t)row * 384;
  float v[6];
  float m = -INFINITY;
#pragma unroll
  for (int t = 0; t < 6; ++t) { v[t] = ptr[lane + 64 * t]; m = fmaxf(m, v[t]); }
#pragma unroll
  for (int off = 32; off; off >>= 1) m = fmaxf(m, __shfl_xor(m, off));
  float ssum = 0.f;
#pragma unroll
  for (int t = 0; t < 6; ++t) { v[t] = __expf(v[t] - m); ssum += v[t]; }
#pragma unroll
  for (int off = 32; off; off >>= 1) ssum += __shfl_xor(ssum, off);
  const float inv = 1.f / ssum;
#pragma unroll
  for (int t = 0; t < 6; ++t) ptr[lane + 64 * t] = v[t] * inv;
}

// PV: O[i][q][h*64+dv] = sum_k attn[i][h][q][k] * V[j(k)][k%128][h*64+dv]
// grid (qt=8, h=16, i=3); wave handles 4 q rows, lane = dv
__global__ __launch_bounds__(256) void pv_kernel(const float* __restrict__ att,
                                                 const float* __restrict__ Vb,
                                                 float* __restrict__ O)
{
  const int qt = blockIdx.x, h = blockIdx.y, i = blockIdx.z;
  const int wave = threadIdx.x >> 6, lane = threadIdx.x & 63;
  const int qbase = qt * 16 + wave * 4;
  const float* arow = att + (((size_t)i * 16 + h) * 128 + qbase) * 384;
  float acc[4] = {0.f, 0.f, 0.f, 0.f};
#pragma unroll 2
  for (int k = 0; k < 384; k += 4) {
    const int j = k >> 7, kk = k & 127;
    const float* vp = Vb + (size_t)j * (LL * 1024) + (size_t)kk * 1024 + h * 64 + lane;
    const float vv0 = vp[0], vv1 = vp[1024], vv2 = vp[2048], vv3 = vp[3072];
#pragma unroll
    for (int qi = 0; qi < 4; ++qi) {
      const float4 a = *(const float4*)(arow + (size_t)qi * 384 + k);
      acc[qi] += a.x * vv0 + a.y * vv1 + a.z * vv2 + a.w * vv3;
    }
  }
#pragma unroll
  for (int qi = 0; qi < 4; ++qi)
    O[(size_t)i * (LL * 1024) + (size_t)(qbase + qi) * 1024 + h * 64 + lane] = acc[qi];
}

// fc: O2 = O @ w_fc ; grid (16,2,3)
__global__ __launch_bounds__(256) void fc_gemm(const float* __restrict__ O,
                                               const float* __restrict__ wfc,
                                               float* __restrict__ O2)
{
  const int i = blockIdx.z;
  gemm64_body(O + (size_t)i * (LL * 1024), wfc, O2 + (size_t)i * (LL * 1024),
              nullptr, 1024, 1024, 1024, blockIdx.y * 64, blockIdx.x * 64);
}

// LayerNorm(o2 + residual) * g + b ; one block per row (384 rows)
__global__ __launch_bounds__(256) void ln_kernel(
    const float* __restrict__ O2, const float* __restrict__ x0,
    const float* __restrict__ x1, const float* __restrict__ x2,
    const float* __restrict__ g, const float* __restrict__ bta,
    float* __restrict__ out)
{
  const int row = blockIdx.x;
  const int i = row >> 7, l = row & 127;
  const float* xr = ((i == 0) ? x0 : (i == 1) ? x1 : x2) + (size_t)l * 1024;
  const float* o2 = O2 + (size_t)i * (LL * 1024) + (size_t)l * 1024;
  const int tid = threadIdx.x;
  float4 v = *(const float4*)(o2 + tid * 4);
  const float4 xv = *(const float4*)(xr + tid * 4);
  v.x += xv.x; v.y += xv.y; v.z += xv.z; v.w += xv.w;
  float s = v.x + v.y + v.z + v.w;
  float s2 = v.x * v.x + v.y * v.y + v.z * v.z + v.w * v.w;
#pragma unroll
  for (int off = 32; off; off >>= 1) {
    s += __shfl_xor(s, off);
    s2 += __shfl_xor(s2, off);
  }
  __shared__ float red[2][4];
  const int wave = tid >> 6, lane = tid & 63;
  if (lane == 0) { red[0][wave] = s; red[1][wave] = s2; }
  __syncthreads();
  s = red[0][0] + red[0][1] + red[0][2] + red[0][3];
  s2 = red[1][0] + red[1][1] + red[1][2] + red[1][3];
  const float mu = s * (1.f / 1024.f);
  const float var = s2 * (1.f / 1024.f) - mu * mu;
  const float rstd = rsqrtf(var + 1e-6f);
  const float4 gv = *(const float4*)(g + tid * 4);
  const float4 bv = *(const float4*)(bta + tid * 4);
  float4 o;
  o.x = (v.x - mu) * rstd * gv.x + bv.x;
  o.y = (v.y - mu) * rstd * gv.y + bv.y;
  o.z = (v.z - mu) * rstd * gv.z + bv.z;
  o.w = (v.w - mu) * rstd * gv.w + bv.w;
  *(float4*)(out + (size_t)row * 1024 + tid * 4) = o;
}

extern "C" void kernel_launch(void* const* d_in, const int* in_sizes, int n_in,
                              void* d_out, int out_size, void* d_ws, size_t ws_size,
                              hipStream_t stream)
{
  const float* x0  = (const float*)d_in[0];
  const float* x1  = (const float*)d_in[1];
  const float* x2  = (const float*)d_in[2];
  const float* wq  = (const float*)d_in[3];
  const float* wk  = (const float*)d_in[4];
  const float* wv  = (const float*)d_in[5];
  const float* wfc = (const float*)d_in[6];
  const float* wd0 = (const float*)d_in[7];
  const float* wd1 = (const float*)d_in[8];
  const float* w1  = (const float*)d_in[9];
  const float* b1  = (const float*)d_in[10];
  const float* w2  = (const float*)d_in[11];
  const float* b2  = (const float*)d_in[12];
  const float* lng = (const float*)d_in[13];
  const float* lnb = (const float*)d_in[14];
  float* ws  = (float*)d_ws;
  float* out = (float*)d_out;

  hipMemsetAsync(ws + OFF_DEC, 0, (size_t)9 * 128 * 128 * sizeof(float), stream);
  proj_gemm<<<dim3(16, 2, 15), 256, 0, stream>>>(x0, x1, x2, wq, wk, wv, wd0, wd1, ws);
  u_gemm<<<dim3(32, 2, 6), 256, 0, stream>>>(w1, b1, ws);
  dec_kernel<<<dim3(2, 4, 36), 256, 0, stream>>>(ws + OFF_U1, ws + OFF_U0, w2, ws + OFF_DEC);
  scores_kernel<<<dim3(9, 16, 2), 256, 0, stream>>>(ws + OFF_Q, ws + OFF_K, ws + OFF_DEC,
                                                    b2, ws + OFF_ATT);
  softmax_kernel<<<1536, 256, 0, stream>>>(ws + OFF_ATT);
  pv_kernel<<<dim3(8, 16, 3), 256, 0, stream>>>(ws + OFF_ATT, ws + OFF_V, ws + OFF_O);
  fc_gemm<<<dim3(16, 2, 3), 256, 0, stream>>>(ws + OFF_O, wfc, ws + OFF_O2);
  ln_kernel<<<384, 256, 0, stream>>>(ws + OFF_O2, x0, x1, x2, lng, lnb, out);
}

// Round 2
// 183.686 us; speedup vs baseline: 1.5794x; 1.5794x over previous
//
#include <hip/hip_runtime.h>
#include <math.h>

#define NEGV (-1e9f)

typedef __attribute__((ext_vector_type(8))) short bf16x8;
typedef __attribute__((ext_vector_type(4))) float f32x4;

// ---------------- workspace layout (byte offsets) ----------------
constexpr size_t OFFB_XB   = 0;         // bf16 [3][128][1024]   786432 B
constexpr size_t OFFB_QB   = 786432;    // bf16 [3][128][1024]
constexpr size_t OFFB_KB   = 1572864;
constexpr size_t OFFB_VB   = 2359296;
constexpr size_t OFFB_D0B  = 3145728;
constexpr size_t OFFB_D1B  = 3932160;
constexpr size_t OFFB_OB   = 4718592;
constexpr size_t OFFB_DEC  = 5505024;   // f32 [9][128][128]     589824 B
constexpr size_t OFFB_WFCT = 6094848;   // bf16 [1024][1024]     2097152 B
constexpr size_t OFFB_WQT  = 8192000;
constexpr size_t OFFB_WKT  = 10289152;
constexpr size_t OFFB_WVT  = 12386304;
constexpr size_t OFFB_WD0T = 14483456;
constexpr size_t OFFB_WD1T = 16580608;
constexpr size_t OFFB_W1T  = 18677760;  // bf16 [2048][2048]     8388608 B -> end 27066368
// overlays (lifetime-disjoint):
constexpr size_t OFFB_U1   = OFFB_WQT;             // f32 [3][128][2048] (over wqT,wkT)
constexpr size_t OFFB_U0   = OFFB_WQT + 3145728;   // f32 [3][128][2048] (over wkT,wvT)
constexpr size_t OFFB_ATT  = OFFB_WD1T;            // f32 [3][16][128][384] (over wd1T,w1T)
constexpr size_t OFFB_O2   = OFFB_WD1T;            // f32 [3][128][1024] (after ATT dead)

__device__ __forceinline__ unsigned short f2bf(float f) {
  unsigned int u = __float_as_uint(f);
  unsigned int r = (u + 0x7fffu + ((u >> 16) & 1u)) >> 16;
  return (unsigned short)r;
}
__device__ __forceinline__ float bf2f(unsigned short u) {
  return __uint_as_float(((unsigned int)u) << 16);
}

// ---------------- convert + transpose pass ----------------
// blocks [0,192): x -> bf16 ; [192,1728): 6 square weights transposed ;
// [1728,2752): w1 (2048x2048) transposed.
__global__ __launch_bounds__(256) void convert_kernel(
    const float* __restrict__ x0, const float* __restrict__ x1, const float* __restrict__ x2,
    const float* __restrict__ wq, const float* __restrict__ wk, const float* __restrict__ wv,
    const float* __restrict__ wd0, const float* __restrict__ wd1,
    const float* __restrict__ wfc, const float* __restrict__ w1,
    char* __restrict__ wsb)
{
  const int b = blockIdx.x, tid = threadIdx.x;
  if (b < 192) {
    const int s = b >> 6;
    const int off = (b & 63) * 2048 + tid * 8;
    const float* src = ((s == 0) ? x0 : (s == 1) ? x1 : x2) + off;
    unsigned short* dst = (unsigned short*)(wsb + OFFB_XB) + (size_t)s * 131072 + off;
    float4 v0 = *(const float4*)src;
    float4 v1 = *(const float4*)(src + 4);
    bf16x8 o;
    o[0] = (short)f2bf(v0.x); o[1] = (short)f2bf(v0.y);
    o[2] = (short)f2bf(v0.z); o[3] = (short)f2bf(v0.w);
    o[4] = (short)f2bf(v1.x); o[5] = (short)f2bf(v1.y);
    o[6] = (short)f2bf(v1.z); o[7] = (short)f2bf(v1.w);
    *(bf16x8*)dst = o;
    return;
  }
  __shared__ unsigned short Ls[64][80];
  const float* src;
  unsigned short* dst;
  int dim, tk, tn;
  int bb = b - 192;
  if (bb < 1536) {
    const int wi = bb >> 8, t = bb & 255;
    switch (wi) {
      case 0: src = wq;  dst = (unsigned short*)(wsb + OFFB_WQT);  break;
      case 1: src = wk;  dst = (unsigned short*)(wsb + OFFB_WKT);  break;
      case 2: src = wv;  dst = (unsigned short*)(wsb + OFFB_WVT);  break;
      case 3: src = wd0; dst = (unsigned short*)(wsb + OFFB_WD0T); break;
      case 4: src = wd1; dst = (unsigned short*)(wsb + OFFB_WD1T); break;
      default: src = wfc; dst = (unsigned short*)(wsb + OFFB_WFCT); break;
    }
    dim = 1024; tk = t >> 4; tn = t & 15;
  } else {
    const int t = bb - 1536;
    src = w1; dst = (unsigned short*)(wsb + OFFB_W1T);
    dim = 2048; tk = t >> 5; tn = t & 31;
  }
  const int r = tid >> 2, c0 = (tid & 3) << 4;
  const float* s = src + (size_t)(tk * 64 + r) * dim + tn * 64 + c0;
#pragma unroll
  for (int u = 0; u < 16; u += 4) {
    float4 v = *(const float4*)(s + u);
    Ls[c0 + u + 0][r] = f2bf(v.x);
    Ls[c0 + u + 1][r] = f2bf(v.y);
    Ls[c0 + u + 2][r] = f2bf(v.z);
    Ls[c0 + u + 3][r] = f2bf(v.w);
  }
  __syncthreads();
  unsigned short* d = dst + (size_t)(tn * 64 + r) * dim + tk * 64 + c0;
  *(uint4*)(d) = *(const uint4*)&Ls[r][c0];
  *(uint4*)(d + 8) = *(const uint4*)&Ls[r][c0 + 8];
}

// ---------------- shared MFMA GEMM body: C[128 x 64-tile] = A @ B ----------------
// A: bf16 [128][lda] row-major. BT: bf16 rows = output col n (pre-offset), [64][ldb].
// Writes either bf16 (Cb) or f32 (Cf). 256 threads = 4 waves, wave w owns rows 32w..32w+31.
__device__ __forceinline__ void mfma_gemm128(
    const short* __restrict__ A, int lda,
    const short* __restrict__ BT, int ldb,
    unsigned short* __restrict__ Cb, float* __restrict__ Cf, int ldc,
    const float* __restrict__ bias, int K)
{
  __shared__ short As[128][40];
  __shared__ short Bs[64][40];
  const int tid = threadIdx.x;
  const int w = tid >> 6, l = tid & 63;
  const int lg = l >> 4, lr = l & 15;
  f32x4 acc[2][4] = {};
  for (int k0 = 0; k0 < K; k0 += 32) {
#pragma unroll
    for (int c = 0; c < 2; ++c) {
      const int ch = tid + 256 * c;
      const int row = ch >> 2, kc = (ch & 3) << 3;
      *(bf16x8*)&As[row][kc] = *(const bf16x8*)(A + (size_t)row * lda + k0 + kc);
    }
    {
      const int n = tid >> 2, kc = (tid & 3) << 3;
      *(bf16x8*)&Bs[n][kc] = *(const bf16x8*)(BT + (size_t)n * ldb + k0 + kc);
    }
    __syncthreads();
    bf16x8 a0 = *(const bf16x8*)&As[32 * w + lr][lg * 8];
    bf16x8 a1 = *(const bf16x8*)&As[32 * w + 16 + lr][lg * 8];
    bf16x8 bfr[4];
#pragma unroll
    for (int fc = 0; fc < 4; ++fc)
      bfr[fc] = *(const bf16x8*)&Bs[16 * fc + lr][lg * 8];
#pragma unroll
    for (int fc = 0; fc < 4; ++fc) {
      acc[0][fc] = __builtin_amdgcn_mfma_f32_16x16x32_bf16(a0, bfr[fc], acc[0][fc], 0, 0, 0);
      acc[1][fc] = __builtin_amdgcn_mfma_f32_16x16x32_bf16(a1, bfr[fc], acc[1][fc], 0, 0, 0);
    }
    __syncthreads();
  }
#pragma unroll
  for (int fr = 0; fr < 2; ++fr)
#pragma unroll
    for (int fc = 0; fc < 4; ++fc)
#pragma unroll
      for (int j = 0; j < 4; ++j) {
        const int row = 32 * w + 16 * fr + lg * 4 + j;
        const int col = 16 * fc + lr;
        float v = acc[fr][fc][j];
        if (bias) v += bias[col];
        if (Cb) Cb[(size_t)row * ldc + col] = f2bf(v);
        else    Cf[(size_t)row * ldc + col] = v;
      }
}

// proj: grid (16 ntile, 15 = s*5+wi). Outputs Qb/Kb/Vb/D0b/D1b (bf16).
__global__ __launch_bounds__(256) void proj_mfma(char* __restrict__ wsb)
{
  const int n0 = blockIdx.x * 64;
  const int z = blockIdx.y;
  const int s = z / 5, wi = z % 5;
  size_t wtoff, coff;
  switch (wi) {
    case 0:  wtoff = OFFB_WQT;  coff = OFFB_QB;  break;
    case 1:  wtoff = OFFB_WKT;  coff = OFFB_KB;  break;
    case 2:  wtoff = OFFB_WVT;  coff = OFFB_VB;  break;
    case 3:  wtoff = OFFB_WD0T; coff = OFFB_D0B; break;
    default: wtoff = OFFB_WD1T; coff = OFFB_D1B; break;
  }
  const short* A  = (const short*)(wsb + OFFB_XB) + (size_t)s * 131072;
  const short* BT = (const short*)(wsb + wtoff) + (size_t)n0 * 1024;
  unsigned short* Cb = (unsigned short*)(wsb + coff) + (size_t)s * 131072 + n0;
  mfma_gemm128(A, 1024, BT, 1024, Cb, nullptr, 1024, nullptr, 1024);
}

// u: grid (32 ntile, 6 = which*3+s). U1 = D1b@w1T[:, :1024] + b1 ; U0 = D0b@w1T[:, 1024:]
__global__ __launch_bounds__(256) void u_mfma(const float* __restrict__ b1, char* __restrict__ wsb)
{
  const int n0 = blockIdx.x * 64;
  const int z = blockIdx.y;
  const int which = z / 3, s = z % 3;
  const short* A = (const short*)(wsb + (which == 0 ? OFFB_D1B : OFFB_D0B)) + (size_t)s * 131072;
  const short* BT = (const short*)(wsb + OFFB_W1T) + (size_t)n0 * 2048 + which * 1024;
  float* Cf = (float*)(wsb + (which == 0 ? OFFB_U1 : OFFB_U0)) + (size_t)s * 262144 + n0;
  const float* bias = (which == 0) ? (b1 + n0) : nullptr;
  mfma_gemm128(A, 1024, BT, 2048, nullptr, Cf, 2048, bias, 1024);
}

// fc: grid (16 ntile, 3 s). O2 = Ob @ wfcT
__global__ __launch_bounds__(256) void fc_mfma(char* __restrict__ wsb)
{
  const int n0 = blockIdx.x * 64;
  const int s = blockIdx.y;
  const short* A = (const short*)(wsb + OFFB_OB) + (size_t)s * 131072;
  const short* BT = (const short*)(wsb + OFFB_WFCT) + (size_t)n0 * 1024;
  float* Cf = (float*)(wsb + OFFB_O2) + (size_t)s * 131072 + n0;
  mfma_gemm128(A, 1024, BT, 1024, nullptr, Cf, 1024, nullptr, 1024);
}

// ---------------- decision accumulator (fp32 vector) ----------------
#define RELU_DOT(AV, BV)                                                      \
  (fmaxf(AV.x + BV.x, 0.f) * w4.x + fmaxf(AV.y + BV.y, 0.f) * w4.y +          \
   fmaxf(AV.z + BV.z, 0.f) * w4.z + fmaxf(AV.w + BV.w, 0.f) * w4.w)

__global__ __launch_bounds__(256) void dec_kernel(
    const float* __restrict__ u1base, const float* __restrict__ u0base,
    const float* __restrict__ w2, float* __restrict__ decacc)
{
  __shared__ float U1s[32][132];
  __shared__ float U0s[64][132];
  __shared__ float wds[128];
  const int z = blockIdx.z;
  const int p = z >> 2, cc = z & 3;
  const int i = p / 3, j = p % 3;
  const int k0 = blockIdx.x * 64, q0 = blockIdx.y * 32;
  const float* u1 = u1base + (size_t)j * (128 * 2048) + (size_t)q0 * 2048;
  const float* u0 = u0base + (size_t)i * (128 * 2048) + (size_t)k0 * 2048;
  const int tid = threadIdx.x;
  const int ty = tid >> 4, tx = tid & 15;
  float acc[2][4] = {};
  for (int stage = 0; stage < 4; ++stage) {
    const int cbase = cc * 512 + stage * 128;
    {
      const int r = tid >> 3, cg = (tid & 7) << 4;
      const float* src = u1 + (size_t)r * 2048 + cbase + cg;
#pragma unroll
      for (int t = 0; t < 4; ++t)
        *(float4*)&U1s[r][cg + 4 * t] = *(const float4*)(src + 4 * t);
    }
    {
      const int r = tid >> 2, cg = (tid & 3) << 5;
      const float* src = u0 + (size_t)r * 2048 + cbase + cg;
#pragma unroll
      for (int t = 0; t < 8; ++t)
        *(float4*)&U0s[r][cg + 4 * t] = *(const float4*)(src + 4 * t);
    }
    if (tid < 128) {
      const int c = cbase + tid;
      wds[tid] = w2[2 * c + 1] - w2[2 * c + 0];
    }
    __syncthreads();
#pragma unroll 2
    for (int c4 = 0; c4 < 128; c4 += 4) {
      const float4 w4  = *(const float4*)&wds[c4];
      const float4 a0  = *(const float4*)&U1s[ty][c4];
      const float4 a1  = *(const float4*)&U1s[ty + 16][c4];
      const float4 vb0 = *(const float4*)&U0s[tx][c4];
      const float4 vb1 = *(const float4*)&U0s[tx + 16][c4];
      const float4 vb2 = *(const float4*)&U0s[tx + 32][c4];
      const float4 vb3 = *(const float4*)&U0s[tx + 48][c4];
      acc[0][0] += RELU_DOT(a0, vb0); acc[0][1] += RELU_DOT(a0, vb1);
      acc[0][2] += RELU_DOT(a0, vb2); acc[0][3] += RELU_DOT(a0, vb3);
      acc[1][0] += RELU_DOT(a1, vb0); acc[1][1] += RELU_DOT(a1, vb1);
      acc[1][2] += RELU_DOT(a1, vb2); acc[1][3] += RELU_DOT(a1, vb3);
    }
    __syncthreads();
  }
#pragma unroll
  for (int qi = 0; qi < 2; ++qi)
#pragma unroll
    for (int kj = 0; kj < 4; ++kj) {
      const int q = q0 + ty + 16 * qi;
      const int k = k0 + tx + 16 * kj;
      atomicAdd(&decacc[(size_t)p * (128 * 128) + (size_t)q * 128 + k], acc[qi][kj]);
    }
}

// ---------------- scores (bf16 Q/K in, fp32 scores out) ----------------
__global__ __launch_bounds__(256) void scores_kernel(
    const unsigned short* __restrict__ Qb, const unsigned short* __restrict__ Kb,
    const float* __restrict__ decacc, const float* __restrict__ b2,
    float* __restrict__ att)
{
  __shared__ float Qs[64][68];
  __shared__ float Ks[128][68];
  const int p = blockIdx.x, h = blockIdx.y, qt = blockIdx.z;
  const int i = p / 3, j = p % 3;
  const int q0 = qt * 64;
  const int tid = threadIdx.x;
  {
    const int r = tid >> 2, c0 = (tid & 3) << 4;
    const unsigned short* src = Qb + (size_t)i * 131072 + (size_t)(q0 + r) * 1024 + h * 64 + c0;
#pragma unroll
    for (int g = 0; g < 2; ++g) {
      bf16x8 v = *(const bf16x8*)(src + 8 * g);
#pragma unroll
      for (int u = 0; u < 8; ++u) Qs[r][c0 + 8 * g + u] = bf2f((unsigned short)v[u]);
    }
  }
  {
    const int r = tid >> 1, c0 = (tid & 1) << 5;
    const unsigned short* src = Kb + (size_t)j * 131072 + (size_t)r * 1024 + h * 64 + c0;
#pragma unroll
    for (int g = 0; g < 4; ++g) {
      bf16x8 v = *(const bf16x8*)(src + 8 * g);
#pragma unroll
      for (int u = 0; u < 8; ++u) Ks[r][c0 + 8 * g + u] = bf2f((unsigned short)v[u]);
    }
  }
  __syncthreads();
  const int ty = tid >> 4, tx = tid & 15;
  float acc[4][8] = {};
  for (int d = 0; d < 64; d += 4) {
    float4 qv[4], kv[8];
#pragma unroll
    for (int qi = 0; qi < 4; ++qi) qv[qi] = *(const float4*)&Qs[ty + 16 * qi][d];
#pragma unroll
    for (int kj = 0; kj < 8; ++kj) kv[kj] = *(const float4*)&Ks[tx + 16 * kj][d];
#pragma unroll
    for (int qi = 0; qi < 4; ++qi)
#pragma unroll
      for (int kj = 0; kj < 8; ++kj)
        acc[qi][kj] += qv[qi].x * kv[kj].x + qv[qi].y * kv[kj].y +
                       qv[qi].z * kv[kj].z + qv[qi].w * kv[kj].w;
  }
  const float bdiff = b2[1] - b2[0];
#pragma unroll
  for (int qi = 0; qi < 4; ++qi)
#pragma unroll
    for (int kj = 0; kj < 8; ++kj) {
      const int q = q0 + ty + 16 * qi;
      const int k = tx + 16 * kj;
      const float da = decacc[(size_t)p * (128 * 128) + (size_t)q * 128 + k];
      const float s = acc[qi][kj] * 0.125f + ((da + bdiff > 0.f) ? NEGV : 0.f);
      att[(((size_t)i * 16 + h) * 128 + q) * 384 + j * 128 + k] = s;
    }
}

// ---------------- softmax over 384 (one wave per row) ----------------
__global__ __launch_bounds__(256) void softmax_kernel(float* __restrict__ att)
{
  const int wave = threadIdx.x >> 6, lane = threadIdx.x & 63;
  const int row = blockIdx.x * 4 + wave;
  float* ptr = att + (size_t)row * 384;
  float v[6];
  float m = -INFINITY;
#pragma unroll
  for (int t = 0; t < 6; ++t) { v[t] = ptr[lane + 64 * t]; m = fmaxf(m, v[t]); }
#pragma unroll
  for (int off = 32; off; off >>= 1) m = fmaxf(m, __shfl_xor(m, off));
  float ssum = 0.f;
#pragma unroll
  for (int t = 0; t < 6; ++t) { v[t] = __expf(v[t] - m); ssum += v[t]; }
#pragma unroll
  for (int off = 32; off; off >>= 1) ssum += __shfl_xor(ssum, off);
  const float inv = 1.f / ssum;
#pragma unroll
  for (int t = 0; t < 6; ++t) ptr[lane + 64 * t] = v[t] * inv;
}

// ---------------- PV (bf16 V, writes bf16 O) ----------------
__global__ __launch_bounds__(256) void pv_kernel(const float* __restrict__ att,
                                                 const unsigned short* __restrict__ Vb,
                                                 unsigned short* __restrict__ Ob)
{
  const int qt = blockIdx.x, h = blockIdx.y, i = blockIdx.z;
  const int wave = threadIdx.x >> 6, lane = threadIdx.x & 63;
  const int qbase = qt * 16 + wave * 4;
  const float* arow = att + (((size_t)i * 16 + h) * 128 + qbase) * 384;
  float acc[4] = {0.f, 0.f, 0.f, 0.f};
#pragma unroll 2
  for (int k = 0; k < 384; k += 4) {
    const int j = k >> 7, kk = k & 127;
    const unsigned short* vp = Vb + (size_t)j * 131072 + (size_t)kk * 1024 + h * 64 + lane;
    const float vv0 = bf2f(vp[0]), vv1 = bf2f(vp[1024]);
    const float vv2 = bf2f(vp[2048]), vv3 = bf2f(vp[3072]);
#pragma unroll
    for (int qi = 0; qi < 4; ++qi) {
      const float4 a = *(const float4*)(arow + (size_t)qi * 384 + k);
      acc[qi] += a.x * vv0 + a.y * vv1 + a.z * vv2 + a.w * vv3;
    }
  }
#pragma unroll
  for (int qi = 0; qi < 4; ++qi)
    Ob[(size_t)i * 131072 + (size_t)(qbase + qi) * 1024 + h * 64 + lane] = f2bf(acc[qi]);
}

// ---------------- LayerNorm(o2 + x) ----------------
__global__ __launch_bounds__(256) void ln_kernel(
    const float* __restrict__ O2, const float* __restrict__ x0,
    const float* __restrict__ x1, const float* __restrict__ x2,
    const float* __restrict__ g, const float* __restrict__ bta,
    float* __restrict__ out)
{
  const int row = blockIdx.x;
  const int i = row >> 7, l = row & 127;
  const float* xr = ((i == 0) ? x0 : (i == 1) ? x1 : x2) + (size_t)l * 1024;
  const float* o2 = O2 + (size_t)i * 131072 + (size_t)l * 1024;
  const int tid = threadIdx.x;
  float4 v = *(const float4*)(o2 + tid * 4);
  const float4 xv = *(const float4*)(xr + tid * 4);
  v.x += xv.x; v.y += xv.y; v.z += xv.z; v.w += xv.w;
  float s = v.x + v.y + v.z + v.w;
  float s2 = v.x * v.x + v.y * v.y + v.z * v.z + v.w * v.w;
#pragma unroll
  for (int off = 32; off; off >>= 1) {
    s += __shfl_xor(s, off);
    s2 += __shfl_xor(s2, off);
  }
  __shared__ float red[2][4];
  const int wave = tid >> 6, lane = tid & 63;
  if (lane == 0) { red[0][wave] = s; red[1][wave] = s2; }
  __syncthreads();
  s = red[0][0] + red[0][1] + red[0][2] + red[0][3];
  s2 = red[1][0] + red[1][1] + red[1][2] + red[1][3];
  const float mu = s * (1.f / 1024.f);
  const float var = s2 * (1.f / 1024.f) - mu * mu;
  const float rstd = rsqrtf(var + 1e-6f);
  const float4 gv = *(const float4*)(g + tid * 4);
  const float4 bv = *(const float4*)(bta + tid * 4);
  float4 o;
  o.x = (v.x - mu) * rstd * gv.x + bv.x;
  o.y = (v.y - mu) * rstd * gv.y + bv.y;
  o.z = (v.z - mu) * rstd * gv.z + bv.z;
  o.w = (v.w - mu) * rstd * gv.w + bv.w;
  *(float4*)(out + (size_t)row * 1024 + tid * 4) = o;
}

extern "C" void kernel_launch(void* const* d_in, const int* in_sizes, int n_in,
                              void* d_out, int out_size, void* d_ws, size_t ws_size,
                              hipStream_t stream)
{
  const float* x0  = (const float*)d_in[0];
  const float* x1  = (const float*)d_in[1];
  const float* x2  = (const float*)d_in[2];
  const float* wq  = (const float*)d_in[3];
  const float* wk  = (const float*)d_in[4];
  const float* wv  = (const float*)d_in[5];
  const float* wfc = (const float*)d_in[6];
  const float* wd0 = (const float*)d_in[7];
  const float* wd1 = (const float*)d_in[8];
  const float* w1  = (const float*)d_in[9];
  const float* b1  = (const float*)d_in[10];
  const float* w2  = (const float*)d_in[11];
  const float* b2  = (const float*)d_in[12];
  const float* lng = (const float*)d_in[13];
  const float* lnb = (const float*)d_in[14];
  char* wsb = (char*)d_ws;
  float* out = (float*)d_out;

  hipMemsetAsync(wsb + OFFB_DEC, 0, (size_t)9 * 128 * 128 * sizeof(float), stream);
  convert_kernel<<<2752, 256, 0, stream>>>(x0, x1, x2, wq, wk, wv, wd0, wd1, wfc, w1, wsb);
  proj_mfma<<<dim3(16, 15), 256, 0, stream>>>(wsb);
  u_mfma<<<dim3(32, 6), 256, 0, stream>>>(b1, wsb);
  dec_kernel<<<dim3(2, 4, 36), 256, 0, stream>>>(
      (const float*)(wsb + OFFB_U1), (const float*)(wsb + OFFB_U0), w2,
      (float*)(wsb + OFFB_DEC));
  scores_kernel<<<dim3(9, 16, 2), 256, 0, stream>>>(
      (const unsigned short*)(wsb + OFFB_QB), (const unsigned short*)(wsb + OFFB_KB),
      (const float*)(wsb + OFFB_DEC), b2, (float*)(wsb + OFFB_ATT));
  softmax_kernel<<<1536, 256, 0, stream>>>((float*)(wsb + OFFB_ATT));
  pv_kernel<<<dim3(8, 16, 3), 256, 0, stream>>>(
      (const float*)(wsb + OFFB_ATT), (const unsigned short*)(wsb + OFFB_VB),
      (unsigned short*)(wsb + OFFB_OB));
  fc_mfma<<<dim3(16, 3), 256, 0, stream>>>(wsb);
  ln_kernel<<<384, 256, 0, stream>>>((const float*)(wsb + OFFB_O2), x0, x1, x2,
                                     lng, lnb, out);
}

// Round 3
// 165.105 us; speedup vs baseline: 1.7572x; 1.1125x over previous
//
#include <hip/hip_runtime.h>
#include <math.h>

#define NEGV (-1e9f)

typedef __attribute__((ext_vector_type(8))) short bf16x8;
typedef __attribute__((ext_vector_type(4))) float f32x4;

// ---------------- workspace layout (byte offsets) ----------------
constexpr size_t OFFB_XB   = 0;         // bf16 [3][128][1024]
constexpr size_t OFFB_QB   = 786432;
constexpr size_t OFFB_KB   = 1572864;
constexpr size_t OFFB_VB   = 2359296;
constexpr size_t OFFB_D0B  = 3145728;
constexpr size_t OFFB_D1B  = 3932160;
constexpr size_t OFFB_OB   = 4718592;
constexpr size_t OFFB_DEC  = 5505024;   // f32 [9][128][128] mask (0 / NEGV)
constexpr size_t OFFB_WFCT = 6094848;   // bf16 [1024][1024]
constexpr size_t OFFB_WQT  = 8192000;
constexpr size_t OFFB_WKT  = 10289152;
constexpr size_t OFFB_WVT  = 12386304;
constexpr size_t OFFB_WD0T = 14483456;
constexpr size_t OFFB_WD1T = 16580608;
constexpr size_t OFFB_W1T  = 18677760;  // bf16 [2048][2048] -> end 27066368
// overlays (lifetime-disjoint):
constexpr size_t OFFB_U1   = OFFB_WQT;             // f32 [3][128][2048]
constexpr size_t OFFB_U0   = OFFB_WQT + 3145728;   // f32 [3][128][2048]
constexpr size_t OFFB_PART = OFFB_D0B;             // bf16 [8][9][128][128] (over D0B,D1B,OB; dead after combine)
constexpr size_t OFFB_ATT  = OFFB_WD1T;            // f32 [3][16][128][384]
constexpr size_t OFFB_O2   = OFFB_WD1T;            // f32 [3][128][1024] (after ATT dead)

__device__ __forceinline__ unsigned short f2bf(float f) {
  unsigned int u = __float_as_uint(f);
  unsigned int r = (u + 0x7fffu + ((u >> 16) & 1u)) >> 16;
  return (unsigned short)r;
}
__device__ __forceinline__ float bf2f(unsigned short u) {
  return __uint_as_float(((unsigned int)u) << 16);
}

__device__ __forceinline__ void gload16(const void* g, void* l) {
  __builtin_amdgcn_global_load_lds(
      (const __attribute__((address_space(1))) void*)g,
      (__attribute__((address_space(3))) void*)l, 16, 0, 0);
}

// ---------------- convert + transpose pass ----------------
__global__ __launch_bounds__(256) void convert_kernel(
    const float* __restrict__ x0, const float* __restrict__ x1, const float* __restrict__ x2,
    const float* __restrict__ wq, const float* __restrict__ wk, const float* __restrict__ wv,
    const float* __restrict__ wd0, const float* __restrict__ wd1,
    const float* __restrict__ wfc, const float* __restrict__ w1,
    char* __restrict__ wsb)
{
  const int b = blockIdx.x, tid = threadIdx.x;
  if (b < 192) {
    const int s = b >> 6;
    const int off = (b & 63) * 2048 + tid * 8;
    const float* src = ((s == 0) ? x0 : (s == 1) ? x1 : x2) + off;
    unsigned short* dst = (unsigned short*)(wsb + OFFB_XB) + (size_t)s * 131072 + off;
    float4 v0 = *(const float4*)src;
    float4 v1 = *(const float4*)(src + 4);
    bf16x8 o;
    o[0] = (short)f2bf(v0.x); o[1] = (short)f2bf(v0.y);
    o[2] = (short)f2bf(v0.z); o[3] = (short)f2bf(v0.w);
    o[4] = (short)f2bf(v1.x); o[5] = (short)f2bf(v1.y);
    o[6] = (short)f2bf(v1.z); o[7] = (short)f2bf(v1.w);
    *(bf16x8*)dst = o;
    return;
  }
  __shared__ unsigned short Ls[64][80];
  const float* src;
  unsigned short* dst;
  int dim, tk, tn;
  int bb = b - 192;
  if (bb < 1536) {
    const int wi = bb >> 8, t = bb & 255;
    switch (wi) {
      case 0: src = wq;  dst = (unsigned short*)(wsb + OFFB_WQT);  break;
      case 1: src = wk;  dst = (unsigned short*)(wsb + OFFB_WKT);  break;
      case 2: src = wv;  dst = (unsigned short*)(wsb + OFFB_WVT);  break;
      case 3: src = wd0; dst = (unsigned short*)(wsb + OFFB_WD0T); break;
      case 4: src = wd1; dst = (unsigned short*)(wsb + OFFB_WD1T); break;
      default: src = wfc; dst = (unsigned short*)(wsb + OFFB_WFCT); break;
    }
    dim = 1024; tk = t >> 4; tn = t & 15;
  } else {
    const int t = bb - 1536;
    src = w1; dst = (unsigned short*)(wsb + OFFB_W1T);
    dim = 2048; tk = t >> 5; tn = t & 31;
  }
  const int r = tid >> 2, c0 = (tid & 3) << 4;
  const float* s = src + (size_t)(tk * 64 + r) * dim + tn * 64 + c0;
#pragma unroll
  for (int u = 0; u < 16; u += 4) {
    float4 v = *(const float4*)(s + u);
    Ls[c0 + u + 0][r] = f2bf(v.x);
    Ls[c0 + u + 1][r] = f2bf(v.y);
    Ls[c0 + u + 2][r] = f2bf(v.z);
    Ls[c0 + u + 3][r] = f2bf(v.w);
  }
  __syncthreads();
  unsigned short* d = dst + (size_t)(tn * 64 + r) * dim + tk * 64 + c0;
  *(uint4*)(d) = *(const uint4*)&Ls[r][c0];
  *(uint4*)(d + 8) = *(const uint4*)&Ls[r][c0 + 8];
}

// ---------------- MFMA GEMM body: C[128][64-tile] = A @ BT^T, K=1024 ----------
// Double-buffered global_load_lds staging, XOR-swizzled LDS, 1 barrier/K-step.
__device__ __forceinline__ void mfma_gemm_db(
    const short* __restrict__ A, int lda,
    const short* __restrict__ BT, int ldb,
    unsigned short* __restrict__ Cb, float* __restrict__ Cf, int ldc,
    const float* __restrict__ bias)
{
  __shared__ __align__(16) short As[2][8192];   // [128 rows][64 k] swizzled
  __shared__ __align__(16) short Bs[2][4096];   // [64 n][64 k] swizzled
  const int tid = threadIdx.x;
  const int w = tid >> 6, l = tid & 63;
  const int lr = l & 15, lg = l >> 4, sx = lr & 7;
  f32x4 acc[2][4] = {};

  auto stage = [&](int buf, int k0) {
#pragma unroll
    for (int t = 0; t < 4; ++t) {
      const int g = t * 256 + w * 64 + l;
      const int r = g >> 3;
      const int c16 = (g & 7) ^ (r & 7);
      gload16(A + (size_t)r * lda + k0 + c16 * 8, &As[buf][t * 2048 + w * 512]);
    }
#pragma unroll
    for (int t = 0; t < 2; ++t) {
      const int g = t * 256 + w * 64 + l;
      const int n = g >> 3;
      const int c16 = (g & 7) ^ (n & 7);
      gload16(BT + (size_t)n * ldb + k0 + c16 * 8, &Bs[buf][t * 2048 + w * 512]);
    }
  };

  stage(0, 0);
  asm volatile("s_waitcnt vmcnt(0)" ::: "memory");
  __builtin_amdgcn_s_barrier();
  int cur = 0;
  for (int t = 0; t < 16; ++t) {
    if (t + 1 < 16) stage(cur ^ 1, (t + 1) * 64);
#pragma unroll
    for (int kk = 0; kk < 2; ++kk) {
      const int slot = ((kk * 4 + lg) ^ sx) * 8;
      bf16x8 a0 = *(const bf16x8*)&As[cur][(32 * w + lr) * 64 + slot];
      bf16x8 a1 = *(const bf16x8*)&As[cur][(32 * w + 16 + lr) * 64 + slot];
#pragma unroll
      for (int fc = 0; fc < 4; ++fc) {
        bf16x8 b = *(const bf16x8*)&Bs[cur][(16 * fc + lr) * 64 + slot];
        acc[0][fc] = __builtin_amdgcn_mfma_f32_16x16x32_bf16(a0, b, acc[0][fc], 0, 0, 0);
        acc[1][fc] = __builtin_amdgcn_mfma_f32_16x16x32_bf16(a1, b, acc[1][fc], 0, 0, 0);
      }
    }
    asm volatile("s_waitcnt vmcnt(0)" ::: "memory");
    __builtin_amdgcn_s_barrier();
    cur ^= 1;
  }
#pragma unroll
  for (int fr = 0; fr < 2; ++fr)
#pragma unroll
    for (int fc = 0; fc < 4; ++fc)
#pragma unroll
      for (int j = 0; j < 4; ++j) {
        const int row = 32 * w + 16 * fr + lg * 4 + j;
        const int col = 16 * fc + lr;
        float v = acc[fr][fc][j];
        if (bias) v += bias[col];
        if (Cb) Cb[(size_t)row * ldc + col] = f2bf(v);
        else    Cf[(size_t)row * ldc + col] = v;
      }
}

__global__ __launch_bounds__(256) void proj_mfma(char* __restrict__ wsb)
{
  const int n0 = blockIdx.x * 64;
  const int z = blockIdx.y;
  const int s = z / 5, wi = z % 5;
  size_t wtoff, coff;
  switch (wi) {
    case 0:  wtoff = OFFB_WQT;  coff = OFFB_QB;  break;
    case 1:  wtoff = OFFB_WKT;  coff = OFFB_KB;  break;
    case 2:  wtoff = OFFB_WVT;  coff = OFFB_VB;  break;
    case 3:  wtoff = OFFB_WD0T; coff = OFFB_D0B; break;
    default: wtoff = OFFB_WD1T; coff = OFFB_D1B; break;
  }
  const short* A  = (const short*)(wsb + OFFB_XB) + (size_t)s * 131072;
  const short* BT = (const short*)(wsb + wtoff) + (size_t)n0 * 1024;
  unsigned short* Cb = (unsigned short*)(wsb + coff) + (size_t)s * 131072 + n0;
  mfma_gemm_db(A, 1024, BT, 1024, Cb, nullptr, 1024, nullptr);
}

__global__ __launch_bounds__(256) void u_mfma(const float* __restrict__ b1, char* __restrict__ wsb)
{
  const int n0 = blockIdx.x * 64;
  const int z = blockIdx.y;
  const int which = z / 3, s = z % 3;
  const short* A = (const short*)(wsb + (which == 0 ? OFFB_D1B : OFFB_D0B)) + (size_t)s * 131072;
  const short* BT = (const short*)(wsb + OFFB_W1T) + (size_t)n0 * 2048 + which * 1024;
  float* Cf = (float*)(wsb + (which == 0 ? OFFB_U1 : OFFB_U0)) + (size_t)s * 262144 + n0;
  const float* bias = (which == 0) ? (b1 + n0) : nullptr;
  mfma_gemm_db(A, 1024, BT, 2048, nullptr, Cf, 2048, bias);
}

__global__ __launch_bounds__(256) void fc_mfma(char* __restrict__ wsb)
{
  const int n0 = blockIdx.x * 64;
  const int s = blockIdx.y;
  const short* A = (const short*)(wsb + OFFB_OB) + (size_t)s * 131072;
  const short* BT = (const short*)(wsb + OFFB_WFCT) + (size_t)n0 * 1024;
  float* Cf = (float*)(wsb + OFFB_O2) + (size_t)s * 131072 + n0;
  mfma_gemm_db(A, 1024, BT, 1024, nullptr, Cf, 1024, nullptr);
}

// ---------------- decision partials (fp32 vector, atomic-free) ----------------
#define RELU_DOT(AV, BV)                                                      \
  (fmaxf(AV.x + BV.x, 0.f) * w4.x + fmaxf(AV.y + BV.y, 0.f) * w4.y +          \
   fmaxf(AV.z + BV.z, 0.f) * w4.z + fmaxf(AV.w + BV.w, 0.f) * w4.w)

// grid (8 cc, 8 = qt*2+kt, 9 p); block: q32 x k64 x c256 (4 stages of 64)
__global__ __launch_bounds__(256) void dec_kernel(
    const float* __restrict__ u1base, const float* __restrict__ u0base,
    const float* __restrict__ w2, unsigned short* __restrict__ part)
{
  __shared__ float U1s[32][68];
  __shared__ float U0s[64][68];
  __shared__ float wds[64];
  const int cc = blockIdx.x;
  const int qt = blockIdx.y >> 1, kt = blockIdx.y & 1;
  const int p = blockIdx.z;
  const int i = p / 3, j = p % 3;
  const int q0 = qt * 32, k0 = kt * 64;
  const float* u1 = u1base + (size_t)j * 262144 + (size_t)q0 * 2048;
  const float* u0 = u0base + (size_t)i * 262144 + (size_t)k0 * 2048;
  const int tid = threadIdx.x;
  const int ty = tid >> 4, tx = tid & 15;
  float acc[2][4] = {};
  for (int s = 0; s < 4; ++s) {
    const int cbase = cc * 256 + s * 64;
    if (s) __syncthreads();
    {
      const int r = tid >> 3, cg = (tid & 7) << 3;
      const float* src = u1 + (size_t)r * 2048 + cbase + cg;
      *(float4*)&U1s[r][cg] = *(const float4*)src;
      *(float4*)&U1s[r][cg + 4] = *(const float4*)(src + 4);
    }
    {
      const int r = tid >> 2, cg = (tid & 3) << 4;
      const float* src = u0 + (size_t)r * 2048 + cbase + cg;
#pragma unroll
      for (int t = 0; t < 4; ++t)
        *(float4*)&U0s[r][cg + 4 * t] = *(const float4*)(src + 4 * t);
    }
    if (tid < 64) {
      const int c = cbase + tid;
      wds[tid] = w2[2 * c + 1] - w2[2 * c];
    }
    __syncthreads();
#pragma unroll 4
    for (int c4 = 0; c4 < 64; c4 += 4) {
      const float4 w4  = *(const float4*)&wds[c4];
      const float4 a0  = *(const float4*)&U1s[ty][c4];
      const float4 a1  = *(const float4*)&U1s[ty + 16][c4];
      const float4 vb0 = *(const float4*)&U0s[tx][c4];
      const float4 vb1 = *(const float4*)&U0s[tx + 16][c4];
      const float4 vb2 = *(const float4*)&U0s[tx + 32][c4];
      const float4 vb3 = *(const float4*)&U0s[tx + 48][c4];
      acc[0][0] += RELU_DOT(a0, vb0); acc[0][1] += RELU_DOT(a0, vb1);
      acc[0][2] += RELU_DOT(a0, vb2); acc[0][3] += RELU_DOT(a0, vb3);
      acc[1][0] += RELU_DOT(a1, vb0); acc[1][1] += RELU_DOT(a1, vb1);
      acc[1][2] += RELU_DOT(a1, vb2); acc[1][3] += RELU_DOT(a1, vb3);
    }
  }
#pragma unroll
  for (int qi = 0; qi < 2; ++qi)
#pragma unroll
    for (int kj = 0; kj < 4; ++kj) {
      const int q = q0 + ty + 16 * qi;
      const int k = k0 + tx + 16 * kj;
      part[((size_t)cc * 9 + p) * 16384 + (size_t)q * 128 + k] = f2bf(acc[qi][kj]);
    }
}

// combine 8 bf16 partials + bias -> 0 / NEGV mask ; grid 288
__global__ __launch_bounds__(256) void combine_kernel(
    const unsigned short* __restrict__ part, const float* __restrict__ b2,
    float* __restrict__ dec)
{
  const int e = blockIdx.x * 512 + threadIdx.x;
  const float bdiff = b2[1] - b2[0];
#pragma unroll
  for (int t = 0; t < 2; ++t) {
    const int idx = e + t * 256;
    float s = 0.f;
#pragma unroll
    for (int c = 0; c < 8; ++c) s += bf2f(part[(size_t)c * 147456 + idx]);
    dec[idx] = (s + bdiff > 0.f) ? NEGV : 0.f;
  }
}

// ---------------- scores (bf16 Q/K in, fp32 scores + mask out) ----------------
__global__ __launch_bounds__(256) void scores_kernel(
    const unsigned short* __restrict__ Qb, const unsigned short* __restrict__ Kb,
    const float* __restrict__ decmask, float* __restrict__ att)
{
  __shared__ float Qs[64][68];
  __shared__ float Ks[128][68];
  const int p = blockIdx.x, h = blockIdx.y, qt = blockIdx.z;
  const int i = p / 3, j = p % 3;
  const int q0 = qt * 64;
  const int tid = threadIdx.x;
  {
    const int r = tid >> 2, c0 = (tid & 3) << 4;
    const unsigned short* src = Qb + (size_t)i * 131072 + (size_t)(q0 + r) * 1024 + h * 64 + c0;
#pragma unroll
    for (int g = 0; g < 2; ++g) {
      bf16x8 v = *(const bf16x8*)(src + 8 * g);
#pragma unroll
      for (int u = 0; u < 8; ++u) Qs[r][c0 + 8 * g + u] = bf2f((unsigned short)v[u]);
    }
  }
  {
    const int r = tid >> 1, c0 = (tid & 1) << 5;
    const unsigned short* src = Kb + (size_t)j * 131072 + (size_t)r * 1024 + h * 64 + c0;
#pragma unroll
    for (int g = 0; g < 4; ++g) {
      bf16x8 v = *(const bf16x8*)(src + 8 * g);
#pragma unroll
      for (int u = 0; u < 8; ++u) Ks[r][c0 + 8 * g + u] = bf2f((unsigned short)v[u]);
    }
  }
  __syncthreads();
  const int ty = tid >> 4, tx = tid & 15;
  float acc[4][8] = {};
  for (int d = 0; d < 64; d += 4) {
    float4 qv[4], kv[8];
#pragma unroll
    for (int qi = 0; qi < 4; ++qi) qv[qi] = *(const float4*)&Qs[ty + 16 * qi][d];
#pragma unroll
    for (int kj = 0; kj < 8; ++kj) kv[kj] = *(const float4*)&Ks[tx + 16 * kj][d];
#pragma unroll
    for (int qi = 0; qi < 4; ++qi)
#pragma unroll
      for (int kj = 0; kj < 8; ++kj)
        acc[qi][kj] += qv[qi].x * kv[kj].x + qv[qi].y * kv[kj].y +
                       qv[qi].z * kv[kj].z + qv[qi].w * kv[kj].w;
  }
#pragma unroll
  for (int qi = 0; qi < 4; ++qi)
#pragma unroll
    for (int kj = 0; kj < 8; ++kj) {
      const int q = q0 + ty + 16 * qi;
      const int k = tx + 16 * kj;
      const float m = decmask[(size_t)p * 16384 + (size_t)q * 128 + k];
      att[(((size_t)i * 16 + h) * 128 + q) * 384 + j * 128 + k] = acc[qi][kj] * 0.125f + m;
    }
}

// ---------------- softmax over 384 (one wave per row) ----------------
__global__ __launch_bounds__(256) void softmax_kernel(float* __restrict__ att)
{
  const int wave = threadIdx.x >> 6, lane = threadIdx.x & 63;
  const int row = blockIdx.x * 4 + wave;
  float* ptr = att + (size_t)row * 384;
  float v[6];
  float m = -INFINITY;
#pragma unroll
  for (int t = 0; t < 6; ++t) { v[t] = ptr[lane + 64 * t]; m = fmaxf(m, v[t]); }
#pragma unroll
  for (int off = 32; off; off >>= 1) m = fmaxf(m, __shfl_xor(m, off));
  float ssum = 0.f;
#pragma unroll
  for (int t = 0; t < 6; ++t) { v[t] = __expf(v[t] - m); ssum += v[t]; }
#pragma unroll
  for (int off = 32; off; off >>= 1) ssum += __shfl_xor(ssum, off);
  const float inv = 1.f / ssum;
#pragma unroll
  for (int t = 0; t < 6; ++t) ptr[lane + 64 * t] = v[t] * inv;
}

// ---------------- PV (bf16 V, writes bf16 O) ----------------
__global__ __launch_bounds__(256) void pv_kernel(const float* __restrict__ att,
                                                 const unsigned short* __restrict__ Vb,
                                                 unsigned short* __restrict__ Ob)
{
  const int qt = blockIdx.x, h = blockIdx.y, i = blockIdx.z;
  const int wave = threadIdx.x >> 6, lane = threadIdx.x & 63;
  const int qbase = qt * 16 + wave * 4;
  const float* arow = att + (((size_t)i * 16 + h) * 128 + qbase) * 384;
  float acc[4] = {0.f, 0.f, 0.f, 0.f};
#pragma unroll 2
  for (int k = 0; k < 384; k += 4) {
    const int j = k >> 7, kk = k & 127;
    const unsigned short* vp = Vb + (size_t)j * 131072 + (size_t)kk * 1024 + h * 64 + lane;
    const float vv0 = bf2f(vp[0]), vv1 = bf2f(vp[1024]);
    const float vv2 = bf2f(vp[2048]), vv3 = bf2f(vp[3072]);
#pragma unroll
    for (int qi = 0; qi < 4; ++qi) {
      const float4 a = *(const float4*)(arow + (size_t)qi * 384 + k);
      acc[qi] += a.x * vv0 + a.y * vv1 + a.z * vv2 + a.w * vv3;
    }
  }
#pragma unroll
  for (int qi = 0; qi < 4; ++qi)
    Ob[(size_t)i * 131072 + (size_t)(qbase + qi) * 1024 + h * 64 + lane] = f2bf(acc[qi]);
}

// ---------------- LayerNorm(o2 + x) ----------------
__global__ __launch_bounds__(256) void ln_kernel(
    const float* __restrict__ O2, const float* __restrict__ x0,
    const float* __restrict__ x1, const float* __restrict__ x2,
    const float* __restrict__ g, const float* __restrict__ bta,
    float* __restrict__ out)
{
  const int row = blockIdx.x;
  const int i = row >> 7, l = row & 127;
  const float* xr = ((i == 0) ? x0 : (i == 1) ? x1 : x2) + (size_t)l * 1024;
  const float* o2 = O2 + (size_t)i * 131072 + (size_t)l * 1024;
  const int tid = threadIdx.x;
  float4 v = *(const float4*)(o2 + tid * 4);
  const float4 xv = *(const float4*)(xr + tid * 4);
  v.x += xv.x; v.y += xv.y; v.z += xv.z; v.w += xv.w;
  float s = v.x + v.y + v.z + v.w;
  float s2 = v.x * v.x + v.y * v.y + v.z * v.z + v.w * v.w;
#pragma unroll
  for (int off = 32; off; off >>= 1) {
    s += __shfl_xor(s, off);
    s2 += __shfl_xor(s2, off);
  }
  __shared__ float red[2][4];
  const int wave = tid >> 6, lane = tid & 63;
  if (lane == 0) { red[0][wave] = s; red[1][wave] = s2; }
  __syncthreads();
  s = red[0][0] + red[0][1] + red[0][2] + red[0][3];
  s2 = red[1][0] + red[1][1] + red[1][2] + red[1][3];
  const float mu = s * (1.f / 1024.f);
  const float var = s2 * (1.f / 1024.f) - mu * mu;
  const float rstd = rsqrtf(var + 1e-6f);
  const float4 gv = *(const float4*)(g + tid * 4);
  const float4 bv = *(const float4*)(bta + tid * 4);
  float4 o;
  o.x = (v.x - mu) * rstd * gv.x + bv.x;
  o.y = (v.y - mu) * rstd * gv.y + bv.y;
  o.z = (v.z - mu) * rstd * gv.z + bv.z;
  o.w = (v.w - mu) * rstd * gv.w + bv.w;
  *(float4*)(out + (size_t)row * 1024 + tid * 4) = o;
}

extern "C" void kernel_launch(void* const* d_in, const int* in_sizes, int n_in,
                              void* d_out, int out_size, void* d_ws, size_t ws_size,
                              hipStream_t stream)
{
  const float* x0  = (const float*)d_in[0];
  const float* x1  = (const float*)d_in[1];
  const float* x2  = (const float*)d_in[2];
  const float* wq  = (const float*)d_in[3];
  const float* wk  = (const float*)d_in[4];
  const float* wv  = (const float*)d_in[5];
  const float* wfc = (const float*)d_in[6];
  const float* wd0 = (const float*)d_in[7];
  const float* wd1 = (const float*)d_in[8];
  const float* w1  = (const float*)d_in[9];
  const float* b1  = (const float*)d_in[10];
  const float* w2  = (const float*)d_in[11];
  const float* b2  = (const float*)d_in[12];
  const float* lng = (const float*)d_in[13];
  const float* lnb = (const float*)d_in[14];
  char* wsb = (char*)d_ws;
  float* out = (float*)d_out;

  convert_kernel<<<2752, 256, 0, stream>>>(x0, x1, x2, wq, wk, wv, wd0, wd1, wfc, w1, wsb);
  proj_mfma<<<dim3(16, 15), 256, 0, stream>>>(wsb);
  u_mfma<<<dim3(32, 6), 256, 0, stream>>>(b1, wsb);
  dec_kernel<<<dim3(8, 8, 9), 256, 0, stream>>>(
      (const float*)(wsb + OFFB_U1), (const float*)(wsb + OFFB_U0), w2,
      (unsigned short*)(wsb + OFFB_PART));
  combine_kernel<<<288, 256, 0, stream>>>(
      (const unsigned short*)(wsb + OFFB_PART), b2, (float*)(wsb + OFFB_DEC));
  scores_kernel<<<dim3(9, 16, 2), 256, 0, stream>>>(
      (const unsigned short*)(wsb + OFFB_QB), (const unsigned short*)(wsb + OFFB_KB),
      (const float*)(wsb + OFFB_DEC), (float*)(wsb + OFFB_ATT));
  softmax_kernel<<<1536, 256, 0, stream>>>((float*)(wsb + OFFB_ATT));
  pv_kernel<<<dim3(8, 16, 3), 256, 0, stream>>>(
      (const float*)(wsb + OFFB_ATT), (const unsigned short*)(wsb + OFFB_VB),
      (unsigned short*)(wsb + OFFB_OB));
  fc_mfma<<<dim3(16, 3), 256, 0, stream>>>(wsb);
  ln_kernel<<<384, 256, 0, stream>>>((const float*)(wsb + OFFB_O2), x0, x1, x2,
                                     lng, lnb, out);
}

// Round 4
// 116.677 us; speedup vs baseline: 2.4865x; 1.4151x over previous
//
#include <hip/hip_runtime.h>
#include <math.h>

#define NEGV (-1e9f)

typedef __attribute__((ext_vector_type(8))) short bf16x8;
typedef __attribute__((ext_vector_type(4))) float f32x4;
typedef _Float16 h2 __attribute__((ext_vector_type(2)));
typedef _Float16 h4 __attribute__((ext_vector_type(4)));
typedef _Float16 h8 __attribute__((ext_vector_type(8)));

// ---------------- workspace layout (byte offsets) ----------------
constexpr size_t OFFB_XB   = 0;         // bf16 [3][128][1024]
constexpr size_t OFFB_QB   = 786432;    // bf16 [3][128][1024]
constexpr size_t OFFB_KB   = 1572864;   // bf16 [3][128][1024]
constexpr size_t OFFB_VT   = 2359296;   // bf16 [1024 col][384 tok]  (V transposed)
constexpr size_t OFFB_D0B  = 3145728;   // bf16 [3][128][1024]
constexpr size_t OFFB_D1B  = 3932160;
constexpr size_t OFFB_OB   = 4718592;   // bf16 [3][128][1024] (attn out)
constexpr size_t OFFB_DEC  = 5505024;   // u8 [9][128][128] mask
constexpr size_t OFFB_WFCT = 6094848;   // bf16 [1024][1024]
constexpr size_t OFFB_WQT  = 8192000;
constexpr size_t OFFB_WKT  = 10289152;
constexpr size_t OFFB_WVT  = 12386304;
constexpr size_t OFFB_WD0T = 14483456;
constexpr size_t OFFB_WD1T = 16580608;
constexpr size_t OFFB_W1T  = 18677760;  // bf16 [2048][2048] -> end 27066368
// overlays (lifetime-disjoint):
constexpr size_t OFFB_U1   = OFFB_WQT;             // f16 [3][128][2048] (over wqT+)
constexpr size_t OFFB_U0   = OFFB_WQT + 1572864;   // f16 [3][128][2048]
constexpr size_t OFFB_PART = OFFB_D0B;             // f16 [8][9][128][128] (over D0B,D1B,OB)
constexpr size_t OFFB_O2   = OFFB_WD1T;            // f32 [3][128][1024]

__device__ __forceinline__ unsigned short f2bf(float f) {
  unsigned int u = __float_as_uint(f);
  unsigned int r = (u + 0x7fffu + ((u >> 16) & 1u)) >> 16;
  return (unsigned short)r;
}
__device__ __forceinline__ float bf2f(unsigned short u) {
  return __uint_as_float(((unsigned int)u) << 16);
}

__device__ __forceinline__ void gload16(const void* g, void* l) {
  __builtin_amdgcn_global_load_lds(
      (const __attribute__((address_space(1))) void*)g,
      (__attribute__((address_space(3))) void*)l, 16, 0, 0);
}

// ---------------- convert + transpose pass ----------------
__global__ __launch_bounds__(256) void convert_kernel(
    const float* __restrict__ x0, const float* __restrict__ x1, const float* __restrict__ x2,
    const float* __restrict__ wq, const float* __restrict__ wk, const float* __restrict__ wv,
    const float* __restrict__ wd0, const float* __restrict__ wd1,
    const float* __restrict__ wfc, const float* __restrict__ w1,
    char* __restrict__ wsb)
{
  const int b = blockIdx.x, tid = threadIdx.x;
  if (b < 192) {
    const int s = b >> 6;
    const int off = (b & 63) * 2048 + tid * 8;
    const float* src = ((s == 0) ? x0 : (s == 1) ? x1 : x2) + off;
    unsigned short* dst = (unsigned short*)(wsb + OFFB_XB) + (size_t)s * 131072 + off;
    float4 v0 = *(const float4*)src;
    float4 v1 = *(const float4*)(src + 4);
    bf16x8 o;
    o[0] = (short)f2bf(v0.x); o[1] = (short)f2bf(v0.y);
    o[2] = (short)f2bf(v0.z); o[3] = (short)f2bf(v0.w);
    o[4] = (short)f2bf(v1.x); o[5] = (short)f2bf(v1.y);
    o[6] = (short)f2bf(v1.z); o[7] = (short)f2bf(v1.w);
    *(bf16x8*)dst = o;
    return;
  }
  __shared__ unsigned short Ls[64][80];
  const float* src;
  unsigned short* dst;
  int dim, tk, tn;
  int bb = b - 192;
  if (bb < 1536) {
    const int wi = bb >> 8, t = bb & 255;
    switch (wi) {
      case 0: src = wq;  dst = (unsigned short*)(wsb + OFFB_WQT);  break;
      case 1: src = wk;  dst = (unsigned short*)(wsb + OFFB_WKT);  break;
      case 2: src = wv;  dst = (unsigned short*)(wsb + OFFB_WVT);  break;
      case 3: src = wd0; dst = (unsigned short*)(wsb + OFFB_WD0T); break;
      case 4: src = wd1; dst = (unsigned short*)(wsb + OFFB_WD1T); break;
      default: src = wfc; dst = (unsigned short*)(wsb + OFFB_WFCT); break;
    }
    dim = 1024; tk = t >> 4; tn = t & 15;
  } else {
    const int t = bb - 1536;
    src = w1; dst = (unsigned short*)(wsb + OFFB_W1T);
    dim = 2048; tk = t >> 5; tn = t & 31;
  }
  const int r = tid >> 2, c0 = (tid & 3) << 4;
  const float* s = src + (size_t)(tk * 64 + r) * dim + tn * 64 + c0;
#pragma unroll
  for (int u = 0; u < 16; u += 4) {
    float4 v = *(const float4*)(s + u);
    Ls[c0 + u + 0][r] = f2bf(v.x);
    Ls[c0 + u + 1][r] = f2bf(v.y);
    Ls[c0 + u + 2][r] = f2bf(v.z);
    Ls[c0 + u + 3][r] = f2bf(v.w);
  }
  __syncthreads();
  unsigned short* d = dst + (size_t)(tn * 64 + r) * dim + tk * 64 + c0;
  *(uint4*)(d) = *(const uint4*)&Ls[r][c0];
  *(uint4*)(d + 8) = *(const uint4*)&Ls[r][c0 + 8];
}

// ---------------- MFMA GEMM body: C[128][64-tile] = A @ BT^T, K=1024 ----------
// mode: 0 = bf16 row-major, 1 = f32 row-major, 2 = fp16 row-major, 3 = bf16 V-transposed
__device__ __forceinline__ void mfma_gemm_db(
    const short* __restrict__ A, int lda,
    const short* __restrict__ BT, int ldb,
    void* __restrict__ out, int ldc,
    const float* __restrict__ bias, int mode)
{
  __shared__ __align__(16) short As[2][8192];
  __shared__ __align__(16) short Bs[2][4096];
  const int tid = threadIdx.x;
  const int w = tid >> 6, l = tid & 63;
  const int lr = l & 15, lg = l >> 4, sx = lr & 7;
  f32x4 acc[2][4] = {};

  auto stage = [&](int buf, int k0) {
#pragma unroll
    for (int t = 0; t < 4; ++t) {
      const int g = t * 256 + w * 64 + l;
      const int r = g >> 3;
      const int c16 = (g & 7) ^ (r & 7);
      gload16(A + (size_t)r * lda + k0 + c16 * 8, &As[buf][t * 2048 + w * 512]);
    }
#pragma unroll
    for (int t = 0; t < 2; ++t) {
      const int g = t * 256 + w * 64 + l;
      const int n = g >> 3;
      const int c16 = (g & 7) ^ (n & 7);
      gload16(BT + (size_t)n * ldb + k0 + c16 * 8, &Bs[buf][t * 2048 + w * 512]);
    }
  };

  stage(0, 0);
  asm volatile("s_waitcnt vmcnt(0)" ::: "memory");
  __builtin_amdgcn_s_barrier();
  int cur = 0;
  for (int t = 0; t < 16; ++t) {
    if (t + 1 < 16) stage(cur ^ 1, (t + 1) * 64);
#pragma unroll
    for (int kk = 0; kk < 2; ++kk) {
      const int slot = ((kk * 4 + lg) ^ sx) * 8;
      bf16x8 a0 = *(const bf16x8*)&As[cur][(32 * w + lr) * 64 + slot];
      bf16x8 a1 = *(const bf16x8*)&As[cur][(32 * w + 16 + lr) * 64 + slot];
#pragma unroll
      for (int fc = 0; fc < 4; ++fc) {
        bf16x8 b = *(const bf16x8*)&Bs[cur][(16 * fc + lr) * 64 + slot];
        acc[0][fc] = __builtin_amdgcn_mfma_f32_16x16x32_bf16(a0, b, acc[0][fc], 0, 0, 0);
        acc[1][fc] = __builtin_amdgcn_mfma_f32_16x16x32_bf16(a1, b, acc[1][fc], 0, 0, 0);
      }
    }
    asm volatile("s_waitcnt vmcnt(0)" ::: "memory");
    __builtin_amdgcn_s_barrier();
    cur ^= 1;
  }
#pragma unroll
  for (int fr = 0; fr < 2; ++fr)
#pragma unroll
    for (int fc = 0; fc < 4; ++fc)
#pragma unroll
      for (int j = 0; j < 4; ++j) {
        const int row = 32 * w + 16 * fr + lg * 4 + j;
        const int col = 16 * fc + lr;
        float v = acc[fr][fc][j];
        if (bias) v += bias[col];
        if (mode == 0) {
          ((unsigned short*)out)[(size_t)row * ldc + col] = f2bf(v);
        } else if (mode == 1) {
          ((float*)out)[(size_t)row * ldc + col] = v;
        } else if (mode == 2) {
          ((unsigned short*)out)[(size_t)row * ldc + col] =
              __builtin_bit_cast(unsigned short, (_Float16)v);
        } else {
          ((unsigned short*)out)[(size_t)col * 384 + row] = f2bf(v);
        }
      }
}

__global__ __launch_bounds__(256) void proj_mfma(char* __restrict__ wsb)
{
  const int n0 = blockIdx.x * 64;
  const int z = blockIdx.y;
  const int s = z / 5, wi = z % 5;
  size_t wtoff;
  switch (wi) {
    case 0:  wtoff = OFFB_WQT;  break;
    case 1:  wtoff = OFFB_WKT;  break;
    case 2:  wtoff = OFFB_WVT;  break;
    case 3:  wtoff = OFFB_WD0T; break;
    default: wtoff = OFFB_WD1T; break;
  }
  const short* A  = (const short*)(wsb + OFFB_XB) + (size_t)s * 131072;
  const short* BT = (const short*)(wsb + wtoff) + (size_t)n0 * 1024;
  if (wi == 2) {
    unsigned short* vt = (unsigned short*)(wsb + OFFB_VT) + (size_t)n0 * 384 + s * 128;
    mfma_gemm_db(A, 1024, BT, 1024, vt, 384, nullptr, 3);
  } else {
    size_t coff = (wi == 0) ? OFFB_QB : (wi == 1) ? OFFB_KB : (wi == 3) ? OFFB_D0B : OFFB_D1B;
    unsigned short* Cb = (unsigned short*)(wsb + coff) + (size_t)s * 131072 + n0;
    mfma_gemm_db(A, 1024, BT, 1024, Cb, 1024, nullptr, 0);
  }
}

__global__ __launch_bounds__(256) void u_mfma(const float* __restrict__ b1, char* __restrict__ wsb)
{
  const int n0 = blockIdx.x * 64;
  const int z = blockIdx.y;
  const int which = z / 3, s = z % 3;
  const short* A = (const short*)(wsb + (which == 0 ? OFFB_D1B : OFFB_D0B)) + (size_t)s * 131072;
  const short* BT = (const short*)(wsb + OFFB_W1T) + (size_t)n0 * 2048 + which * 1024;
  unsigned short* Ch = (unsigned short*)(wsb + (which == 0 ? OFFB_U1 : OFFB_U0)) +
                       (size_t)s * 262144 + n0;
  const float* bias = (which == 0) ? (b1 + n0) : nullptr;
  mfma_gemm_db(A, 1024, BT, 2048, Ch, 2048, bias, 2);
}

__global__ __launch_bounds__(256) void fc_mfma(char* __restrict__ wsb)
{
  const int n0 = blockIdx.x * 64;
  const int s = blockIdx.y;
  const short* A = (const short*)(wsb + OFFB_OB) + (size_t)s * 131072;
  const short* BT = (const short*)(wsb + OFFB_WFCT) + (size_t)n0 * 1024;
  float* Cf = (float*)(wsb + OFFB_O2) + (size_t)s * 131072 + n0;
  mfma_gemm_db(A, 1024, BT, 1024, Cf, 1024, nullptr, 1);
}

// ---------------- decision partials (packed fp16 + v_dot2_f32_f16) ----------------
#define DOT8(ACC, T, W)                                                                        \
  ACC = __builtin_amdgcn_fdot2(__builtin_shufflevector(T, T, 0, 1),                            \
                               __builtin_shufflevector(W, W, 0, 1), ACC, false);               \
  ACC = __builtin_amdgcn_fdot2(__builtin_shufflevector(T, T, 2, 3),                            \
                               __builtin_shufflevector(W, W, 2, 3), ACC, false);               \
  ACC = __builtin_amdgcn_fdot2(__builtin_shufflevector(T, T, 4, 5),                            \
                               __builtin_shufflevector(W, W, 4, 5), ACC, false);               \
  ACC = __builtin_amdgcn_fdot2(__builtin_shufflevector(T, T, 6, 7),                            \
                               __builtin_shufflevector(W, W, 6, 7), ACC, false);

// grid (8 cc, 8 = qt*2+kt, 9 p); block: q32 x k64 x c256 (2 stages of 128)
__global__ __launch_bounds__(256) void dec_kernel(
    const unsigned short* __restrict__ u1base, const unsigned short* __restrict__ u0base,
    const float* __restrict__ w2, unsigned short* __restrict__ part)
{
  __shared__ unsigned short U1s[32][136];
  __shared__ unsigned short U0s[64][136];
  __shared__ h2 wds[64];
  const int cc = blockIdx.x;
  const int qt = blockIdx.y >> 1, kt = blockIdx.y & 1;
  const int p = blockIdx.z;
  const int i = p / 3, j = p % 3;
  const int q0 = qt * 32, k0 = kt * 64;
  const unsigned short* u1 = u1base + (size_t)j * 262144 + (size_t)q0 * 2048;
  const unsigned short* u0 = u0base + (size_t)i * 262144 + (size_t)k0 * 2048;
  const int tid = threadIdx.x;
  const int ty = tid >> 4, tx = tid & 15;
  const h8 zero8 = {};
  float acc[2][4] = {};
  for (int s = 0; s < 2; ++s) {
    const int cbase = cc * 256 + s * 128;
    if (s) __syncthreads();
#pragma unroll
    for (int t = 0; t < 2; ++t) {
      const int g = tid + t * 256;
      const int r = g >> 4, c8 = (g & 15) << 3;
      *(uint4*)&U1s[r][c8] = *(const uint4*)(u1 + (size_t)r * 2048 + cbase + c8);
    }
#pragma unroll
    for (int t = 0; t < 4; ++t) {
      const int g = tid + t * 256;
      const int r = g >> 4, c8 = (g & 15) << 3;
      *(uint4*)&U0s[r][c8] = *(const uint4*)(u0 + (size_t)r * 2048 + cbase + c8);
    }
    if (tid < 64) {
      const int c = cbase + tid * 2;
      h2 wv;
      wv[0] = (_Float16)(w2[2 * c + 1] - w2[2 * c]);
      wv[1] = (_Float16)(w2[2 * c + 3] - w2[2 * c + 2]);
      wds[tid] = wv;
    }
    __syncthreads();
#pragma unroll 4
    for (int c8 = 0; c8 < 128; c8 += 8) {
      h8 wv = *(const h8*)&wds[c8 >> 1];
      h8 a0 = *(const h8*)&U1s[ty][c8];
      h8 a1 = *(const h8*)&U1s[ty + 16][c8];
      h8 b0 = *(const h8*)&U0s[tx][c8];
      h8 b1 = *(const h8*)&U0s[tx + 16][c8];
      h8 b2v = *(const h8*)&U0s[tx + 32][c8];
      h8 b3 = *(const h8*)&U0s[tx + 48][c8];
      h8 t;
      t = __builtin_elementwise_max(a0 + b0, zero8);  DOT8(acc[0][0], t, wv);
      t = __builtin_elementwise_max(a0 + b1, zero8);  DOT8(acc[0][1], t, wv);
      t = __builtin_elementwise_max(a0 + b2v, zero8); DOT8(acc[0][2], t, wv);
      t = __builtin_elementwise_max(a0 + b3, zero8);  DOT8(acc[0][3], t, wv);
      t = __builtin_elementwise_max(a1 + b0, zero8);  DOT8(acc[1][0], t, wv);
      t = __builtin_elementwise_max(a1 + b1, zero8);  DOT8(acc[1][1], t, wv);
      t = __builtin_elementwise_max(a1 + b2v, zero8); DOT8(acc[1][2], t, wv);
      t = __builtin_elementwise_max(a1 + b3, zero8);  DOT8(acc[1][3], t, wv);
    }
  }
#pragma unroll
  for (int qi = 0; qi < 2; ++qi)
#pragma unroll
    for (int kj = 0; kj < 4; ++kj) {
      const int q = q0 + ty + 16 * qi;
      const int k = k0 + tx + 16 * kj;
      part[((size_t)cc * 9 + p) * 16384 + (size_t)q * 128 + k] =
          __builtin_bit_cast(unsigned short, (_Float16)acc[qi][kj]);
    }
}

// combine 8 fp16 partials + bias -> byte mask ; grid 144
__global__ __launch_bounds__(256) void combine_kernel(
    const unsigned short* __restrict__ part, const float* __restrict__ b2,
    unsigned char* __restrict__ dec8)
{
  const int idx4 = blockIdx.x * 1024 + threadIdx.x * 4;
  const float bdiff = b2[1] - b2[0];
  float s[4] = {};
#pragma unroll
  for (int c = 0; c < 8; ++c) {
    h4 v = *(const h4*)(part + (size_t)c * 147456 + idx4);
#pragma unroll
    for (int e = 0; e < 4; ++e) s[e] += (float)v[e];
  }
  unsigned int m = 0;
#pragma unroll
  for (int e = 0; e < 4; ++e)
    if (s[e] + bdiff > 0.f) m |= 1u << (8 * e);
  *(unsigned int*)(dec8 + idx4) = m;
}

// ---------------- fused attention: scores + softmax + PV ----------------
// grid (4 qh, 16 h, 3 i), 128 threads = 2 waves; wave owns 16 q rows.
__global__ __launch_bounds__(128) void attn_kernel(
    const unsigned short* __restrict__ Qb, const unsigned short* __restrict__ Kb,
    const unsigned short* __restrict__ VT, const unsigned char* __restrict__ dec8,
    unsigned short* __restrict__ Ob)
{
  __shared__ unsigned short Vls[64][392];
  __shared__ unsigned short Plds[2][16][392];
  const int qh = blockIdx.x, h = blockIdx.y, i = blockIdx.z;
  const int tid = threadIdx.x;
  const int w = tid >> 6, l = tid & 63;
  const int lr = l & 15, lg = l >> 4;

  // stage V^T head slice: VT[(h*64+dv)*384 + k] -> Vls[dv][k]
  {
    const unsigned short* src = VT + (size_t)h * 64 * 384;
#pragma unroll
    for (int c = 0; c < 24; ++c) {
      const int g = c * 128 + tid;
      const int row = g / 48, c8 = (g % 48) * 8;
      *(bf16x8*)&Vls[row][c8] = *(const bf16x8*)(src + (size_t)row * 384 + c8);
    }
  }

  const int q0 = qh * 32 + w * 16;
  const unsigned short* qp =
      Qb + (size_t)i * 131072 + (size_t)(q0 + lr) * 1024 + h * 64 + lg * 8;
  bf16x8 aq0 = *(const bf16x8*)qp;
  bf16x8 aq1 = *(const bf16x8*)(qp + 32);

  f32x4 acc[24];
#pragma unroll
  for (int kt = 0; kt < 24; ++kt) acc[kt] = (f32x4){0.f, 0.f, 0.f, 0.f};
#pragma unroll
  for (int kt = 0; kt < 24; ++kt) {
    const int js = kt >> 3;
    const int kk = (kt & 7) * 16 + lr;
    const unsigned short* kp =
        Kb + (size_t)js * 131072 + (size_t)kk * 1024 + h * 64 + lg * 8;
    bf16x8 b0 = *(const bf16x8*)kp;
    bf16x8 b1 = *(const bf16x8*)(kp + 32);
    acc[kt] = __builtin_amdgcn_mfma_f32_16x16x32_bf16(aq0, b0, acc[kt], 0, 0, 0);
    acc[kt] = __builtin_amdgcn_mfma_f32_16x16x32_bf16(aq1, b1, acc[kt], 0, 0, 0);
  }

  // mask + scale; rows q0+lg*4+j_, cols kt*16+lr (k = js*128 + (kt&7)*16+lr)
  float inv[4];
#pragma unroll
  for (int j_ = 0; j_ < 4; ++j_) {
    const int qrow = q0 + lg * 4 + j_;
#pragma unroll
    for (int kt = 0; kt < 24; ++kt) {
      const int p = i * 3 + (kt >> 3);
      const int kcol = (kt & 7) * 16 + lr;
      const unsigned char m = dec8[(size_t)p * 16384 + (size_t)qrow * 128 + kcol];
      acc[kt][j_] = acc[kt][j_] * 0.125f + (m ? NEGV : 0.f);
    }
    float mx = -INFINITY;
#pragma unroll
    for (int kt = 0; kt < 24; ++kt) mx = fmaxf(mx, acc[kt][j_]);
#pragma unroll
    for (int off = 1; off < 16; off <<= 1) mx = fmaxf(mx, __shfl_xor(mx, off));
    float sm = 0.f;
#pragma unroll
    for (int kt = 0; kt < 24; ++kt) {
      acc[kt][j_] = __expf(acc[kt][j_] - mx);
      sm += acc[kt][j_];
    }
#pragma unroll
    for (int off = 1; off < 16; off <<= 1) sm += __shfl_xor(sm, off);
    inv[j_] = 1.f / sm;
  }

  // P -> LDS (bf16)
#pragma unroll
  for (int kt = 0; kt < 24; ++kt)
#pragma unroll
    for (int j_ = 0; j_ < 4; ++j_)
      Plds[w][lg * 4 + j_][kt * 16 + lr] = f2bf(acc[kt][j_]);
  __syncthreads();

  // PV: O[16q x 64dv] = P[16 x 384] @ Vhead[384 x 64]
  f32x4 accO[4];
#pragma unroll
  for (int dvt = 0; dvt < 4; ++dvt) accO[dvt] = (f32x4){0.f, 0.f, 0.f, 0.f};
#pragma unroll
  for (int ks = 0; ks < 12; ++ks) {
    bf16x8 a = *(const bf16x8*)&Plds[w][lr][ks * 32 + lg * 8];
#pragma unroll
    for (int dvt = 0; dvt < 4; ++dvt) {
      bf16x8 b = *(const bf16x8*)&Vls[dvt * 16 + lr][ks * 32 + lg * 8];
      accO[dvt] = __builtin_amdgcn_mfma_f32_16x16x32_bf16(a, b, accO[dvt], 0, 0, 0);
    }
  }
#pragma unroll
  for (int dvt = 0; dvt < 4; ++dvt)
#pragma unroll
    for (int j_ = 0; j_ < 4; ++j_) {
      const int qrow = q0 + lg * 4 + j_;
      Ob[(size_t)i * 131072 + (size_t)qrow * 1024 + h * 64 + dvt * 16 + lr] =
          f2bf(accO[dvt][j_] * inv[j_]);
    }
}

// ---------------- LayerNorm(o2 + x) ----------------
__global__ __launch_bounds__(256) void ln_kernel(
    const float* __restrict__ O2, const float* __restrict__ x0,
    const float* __restrict__ x1, const float* __restrict__ x2,
    const float* __restrict__ g, const float* __restrict__ bta,
    float* __restrict__ out)
{
  const int row = blockIdx.x;
  const int i = row >> 7, l = row & 127;
  const float* xr = ((i == 0) ? x0 : (i == 1) ? x1 : x2) + (size_t)l * 1024;
  const float* o2 = O2 + (size_t)i * 131072 + (size_t)l * 1024;
  const int tid = threadIdx.x;
  float4 v = *(const float4*)(o2 + tid * 4);
  const float4 xv = *(const float4*)(xr + tid * 4);
  v.x += xv.x; v.y += xv.y; v.z += xv.z; v.w += xv.w;
  float s = v.x + v.y + v.z + v.w;
  float s2 = v.x * v.x + v.y * v.y + v.z * v.z + v.w * v.w;
#pragma unroll
  for (int off = 32; off; off >>= 1) {
    s += __shfl_xor(s, off);
    s2 += __shfl_xor(s2, off);
  }
  __shared__ float red[2][4];
  const int wave = tid >> 6, lane = tid & 63;
  if (lane == 0) { red[0][wave] = s; red[1][wave] = s2; }
  __syncthreads();
  s = red[0][0] + red[0][1] + red[0][2] + red[0][3];
  s2 = red[1][0] + red[1][1] + red[1][2] + red[1][3];
  const float mu = s * (1.f / 1024.f);
  const float var = s2 * (1.f / 1024.f) - mu * mu;
  const float rstd = rsqrtf(var + 1e-6f);
  const float4 gv = *(const float4*)(g + tid * 4);
  const float4 bv = *(const float4*)(bta + tid * 4);
  float4 o;
  o.x = (v.x - mu) * rstd * gv.x + bv.x;
  o.y = (v.y - mu) * rstd * gv.y + bv.y;
  o.z = (v.z - mu) * rstd * gv.z + bv.z;
  o.w = (v.w - mu) * rstd * gv.w + bv.w;
  *(float4*)(out + (size_t)row * 1024 + tid * 4) = o;
}

extern "C" void kernel_launch(void* const* d_in, const int* in_sizes, int n_in,
                              void* d_out, int out_size, void* d_ws, size_t ws_size,
                              hipStream_t stream)
{
  const float* x0  = (const float*)d_in[0];
  const float* x1  = (const float*)d_in[1];
  const float* x2  = (const float*)d_in[2];
  const float* wq  = (const float*)d_in[3];
  const float* wk  = (const float*)d_in[4];
  const float* wv  = (const float*)d_in[5];
  const float* wfc = (const float*)d_in[6];
  const float* wd0 = (const float*)d_in[7];
  const float* wd1 = (const float*)d_in[8];
  const float* w1  = (const float*)d_in[9];
  const float* b1  = (const float*)d_in[10];
  const float* w2  = (const float*)d_in[11];
  const float* b2  = (const float*)d_in[12];
  const float* lng = (const float*)d_in[13];
  const float* lnb = (const float*)d_in[14];
  char* wsb = (char*)d_ws;
  float* out = (float*)d_out;

  convert_kernel<<<2752, 256, 0, stream>>>(x0, x1, x2, wq, wk, wv, wd0, wd1, wfc, w1, wsb);
  proj_mfma<<<dim3(16, 15), 256, 0, stream>>>(wsb);
  u_mfma<<<dim3(32, 6), 256, 0, stream>>>(b1, wsb);
  dec_kernel<<<dim3(8, 8, 9), 256, 0, stream>>>(
      (const unsigned short*)(wsb + OFFB_U1), (const unsigned short*)(wsb + OFFB_U0), w2,
      (unsigned short*)(wsb + OFFB_PART));
  combine_kernel<<<144, 256, 0, stream>>>(
      (const unsigned short*)(wsb + OFFB_PART), b2, (unsigned char*)(wsb + OFFB_DEC));
  attn_kernel<<<dim3(4, 16, 3), 128, 0, stream>>>(
      (const unsigned short*)(wsb + OFFB_QB), (const unsigned short*)(wsb + OFFB_KB),
      (const unsigned short*)(wsb + OFFB_VT), (const unsigned char*)(wsb + OFFB_DEC),
      (unsigned short*)(wsb + OFFB_OB));
  fc_mfma<<<dim3(16, 3), 256, 0, stream>>>(wsb);
  ln_kernel<<<384, 256, 0, stream>>>((const float*)(wsb + OFFB_O2), x0, x1, x2,
                                     lng, lnb, out);
}